// Round 23
// baseline (183.428 us; speedup 1.0000x reference)
//
#include <hip/hip_runtime.h>
#include <cstdint>
#include <cstddef>

#define NPTS 4096
#define BATCH 4
#define FEAT 256
#define KNN 32

// ---------------- workspace layout (bytes) ----------------
static constexpr size_t OFF_IDX  = 0;                            // int32 [B*N*K]   = 2 MB
static constexpr size_t OFF_CNT  = 2u * 1024 * 1024;             // int32 [B*N]     = 64 KB
static constexpr size_t OFF_PART = OFF_CNT + 64u * 1024;         // f32 [256*512]   = 512 KB
static constexpr size_t OFF_SC   = OFF_PART + 512u * 1024;       // f32 [256]
static constexpr size_t OFF_SH   = OFF_SC + 4096;                // f32 [256]
static constexpr size_t OFF_HT2  = OFF_SH + 4096;                // bf16 [B*N*F]    = 8 MB

template<int CTRL>
static __device__ __forceinline__ uint32_t dpp32(uint32_t x) {
    return (uint32_t)__builtin_amdgcn_update_dpp(-1, (int)x, CTRL, 0xF, 0xF, false);
}

// full-wave u32 min; result returned uniform (via lane 63)
static __device__ __forceinline__ uint32_t wave_min_u32(uint32_t v) {
    v = min(v, dpp32<0x111>(v));  // row_shr:1
    v = min(v, dpp32<0x112>(v));  // row_shr:2
    v = min(v, dpp32<0x114>(v));  // row_shr:4
    v = min(v, dpp32<0x118>(v));  // row_shr:8
    v = min(v, dpp32<0x142>(v));  // row_bcast:15
    v = min(v, dpp32<0x143>(v));  // row_bcast:31
    return (uint32_t)__builtin_amdgcn_readlane((int)v, 63);
}

// fp32 -> bf16 round-to-nearest-even (finite values)
static __device__ __forceinline__ unsigned short f2bf(float x) {
    uint32_t u = __float_as_uint(x);
    u += 0x7FFFu + ((u >> 16) & 1u);
    return (unsigned short)(u >> 16);
}
static __device__ __forceinline__ float bf2f(unsigned short h) {
    return __uint_as_float(((uint32_t)h) << 16);
}

// ---------------- KNN body: TWO rows per wave (r14/r16/r18 proven) ----------------
static __device__ __forceinline__ void knn_body2(int gid, const float* __restrict__ xyz,
                                                 int* __restrict__ out_idx,
                                                 int* __restrict__ cnt) {
#pragma clang fp contract(off)
    const int lane = threadIdx.x & 63;
    const int wv = threadIdx.x >> 6;       // 0..3
    const int b = gid >> 9;                // 512 knn-blocks per batch
    const int nA = (gid & 511) * 8 + wv * 2;
    const int nB = nA + 1;
    const float* xb = xyz + (size_t)b * 3 * NPTS;
    const float x0nA = xb[nA], x1nA = xb[NPTS + nA];
    const float sqnA = x0nA * x0nA + x1nA * x1nA;
    const float x0nB = xb[nB], x1nB = xb[NPTS + nB];
    const float sqnB = x0nB * x0nB + x1nB * x1nB;

    const float* xr0 = xb + lane * 64;
    const float* xr1 = xb + NPTS + lane * 64;
    const uint32_t mbase = (uint32_t)(lane * 64);

    uint32_t Ad0 = ~0u, Ad1 = ~0u, Ad2 = ~0u, Ad3 = ~0u;
    uint32_t Ai0 = 0, Ai1 = 0, Ai2 = 0, Ai3 = 0;
    uint32_t Bd0 = ~0u, Bd1 = ~0u, Bd2 = ~0u, Bd3 = ~0u;
    uint32_t Bi0 = 0, Bi1 = 0, Bi2 = 0, Bi3 = 0;

#define QINS(U, MI, D0, D1, D2, D3, I0, I1, I2, I3)                              \
    {                                                                            \
        const bool c0 = (U) < D0, c1 = (U) < D1, c2 = (U) < D2, c3 = (U) < D3;   \
        D3 = c3 ? (c2 ? D2 : (U)) : D3;   I3 = c3 ? (c2 ? I2 : (MI)) : I3;       \
        D2 = c2 ? (c1 ? D1 : (U)) : D2;   I2 = c2 ? (c1 ? I1 : (MI)) : I2;       \
        D1 = c1 ? (c0 ? D0 : (U)) : D1;   I1 = c1 ? (c0 ? I0 : (MI)) : I1;       \
        D0 = c0 ? (U) : D0;               I0 = c0 ? (MI) : I0;                   \
    }
#define UMAP(X0N, X1N, SQN, U)                                                   \
    uint32_t U; {                                                                \
        const float p = __builtin_fmaf((X1N), x1m, (X0N) * x0m);                 \
        const float d = __builtin_fmaf(p, -2.0f, sqm) + (SQN);                   \
        U = __float_as_uint(d);                                                  \
        U ^= (uint32_t)((int32_t)U >> 31) | 0x80000000u;                         \
    }

#pragma unroll 4
    for (int i0 = 0; i0 < 64; i0 += 4) {
        const float4 a0 = *(const float4*)(xr0 + i0);
        const float4 a1 = *(const float4*)(xr1 + i0);
#define CAND2(X0, X1, J)                                                         \
    {                                                                            \
        const float x0m = (X0), x1m = (X1);                                      \
        const float sqm = x0m * x0m + x1m * x1m;   /* shared, ref-identical */   \
        const uint32_t mi = mbase + (uint32_t)(i0 + (J));                        \
        UMAP(x0nA, x1nA, sqnA, uA)                                               \
        QINS(uA, mi, Ad0, Ad1, Ad2, Ad3, Ai0, Ai1, Ai2, Ai3)                     \
        UMAP(x0nB, x1nB, sqnB, uB)                                               \
        QINS(uB, mi, Bd0, Bd1, Bd2, Bd3, Bi0, Bi1, Bi2, Bi3)                     \
    }
        CAND2(a0.x, a1.x, 0)
        CAND2(a0.y, a1.y, 1)
        CAND2(a0.z, a1.z, 2)
        CAND2(a0.w, a1.w, 3)
#undef CAND2
    }

    int navA = 4, navB = 4;
    uint32_t widx = 0;  // lane k: A-winner k; lane 32+k: B-winner k
#pragma unroll 1
    for (int k = 0; k < KNN; ++k) {
        const uint32_t wdA = wave_min_u32(Ad0);
        const uint32_t wdB = wave_min_u32(Bd0);
        const unsigned long long balA = __ballot(Ad0 == wdA);
        const unsigned long long balB = __ballot(Bd0 == wdB);
        const int ownerA = __ffsll((long long)balA) - 1;
        const int ownerB = __ffsll((long long)balB) - 1;
        const uint32_t wmA = (uint32_t)__builtin_amdgcn_readlane((int)Ai0, ownerA);
        const uint32_t wmB = (uint32_t)__builtin_amdgcn_readlane((int)Bi0, ownerB);
        widx = (lane == k) ? wmA : widx;
        widx = (lane == k + 32) ? wmB : widx;
        const bool popA = (lane == ownerA);
        Ad0 = popA ? Ad1 : Ad0;  Ai0 = popA ? Ai1 : Ai0;
        Ad1 = popA ? Ad2 : Ad1;  Ai1 = popA ? Ai2 : Ai1;
        Ad2 = popA ? Ad3 : Ad2;  Ai2 = popA ? Ai3 : Ai2;
        Ad3 = popA ? 0xFFFFFFFFu : Ad3;
        navA -= popA ? 1 : 0;
        const bool popB = (lane == ownerB);
        Bd0 = popB ? Bd1 : Bd0;  Bi0 = popB ? Bi1 : Bi0;
        Bd1 = popB ? Bd2 : Bd1;  Bi1 = popB ? Bi2 : Bi1;
        Bd2 = popB ? Bd3 : Bd2;  Bi2 = popB ? Bi3 : Bi2;
        Bd3 = popB ? 0xFFFFFFFFu : Bd3;
        navB -= popB ? 1 : 0;
        if (navA == 0) {
            Ad0 = Ad1 = Ad2 = Ad3 = ~0u;
            Ai0 = Ai1 = Ai2 = Ai3 = 0;
#pragma unroll 4
            for (int i = 0; i < 64; ++i) {
                const float x0m = xr0[i], x1m = xr1[i];
                const float sqm = x0m * x0m + x1m * x1m;
                UMAP(x0nA, x1nA, sqnA, u)
                const uint32_t mi = mbase + (uint32_t)i;
                const bool keep = (u > wdA) || (u == wdA && mi > wmA);
                u = keep ? u : 0xFFFFFFFFu;
                QINS(u, mi, Ad0, Ad1, Ad2, Ad3, Ai0, Ai1, Ai2, Ai3)
            }
            navA = 4;
        }
        if (navB == 0) {
            Bd0 = Bd1 = Bd2 = Bd3 = ~0u;
            Bi0 = Bi1 = Bi2 = Bi3 = 0;
#pragma unroll 4
            for (int i = 0; i < 64; ++i) {
                const float x0m = xr0[i], x1m = xr1[i];
                const float sqm = x0m * x0m + x1m * x1m;
                UMAP(x0nB, x1nB, sqnB, u)
                const uint32_t mi = mbase + (uint32_t)i;
                const bool keep = (u > wdB) || (u == wdB && mi > wmB);
                u = keep ? u : 0xFFFFFFFFu;
                QINS(u, mi, Bd0, Bd1, Bd2, Bd3, Bi0, Bi1, Bi2, Bi3)
            }
            navB = 4;
        }
    }
    const int nw = (lane < 32) ? nA : nB;
    out_idx[((size_t)b * NPTS + nw) * KNN + (lane & 31)] = (int)widx;
    atomicAdd(&cnt[b * NPTS + (int)widx], 1);
#undef QINS
#undef UMAP
}

// ---------------- fused: knn blocks (2/3) + gemm blocks (1/3) ---------------------
// gemm LDS staged as bf16 (16.5 KB total): blocks/CU rises 4 -> 8, doubling
// resident knn waves (the latency-bound part). fp32 accumulate unchanged.
__global__ __launch_bounds__(256, 4) void fused_knn_gemm(const float* __restrict__ xyz,
                                                         int* __restrict__ out_idx,
                                                         int* __restrict__ cnt,
                                                         const float* __restrict__ feat,
                                                         const float* __restrict__ W,
                                                         const float* __restrict__ bias,
                                                         unsigned short* __restrict__ Ht2) {
    const int bid = blockIdx.x;
    const int g3 = bid / 3, r3 = bid % 3;
    if (r3 < 2) {
        knn_body2(g3 * 2 + r3, xyz, out_idx, cnt);
        return;
    }
    // ---- gemm body: c-tile 64, bf16 LDS tiles ----
    __shared__ unsigned short As[64][64];  // [c][n_local] bf16
    __shared__ unsigned short Bs[64][68];  // [c][f_local] bf16, padded
    const int q = g3;             // [0, 1024)
    const int b = q >> 8;
    const int rr = q & 255;
    const int n0 = (rr >> 2) * 64;
    const int f0 = (rr & 3) * 64;
    const int t = threadIdx.x;
    const int tn = t % 16, tf = t / 16;
    float acc[4][4] = {};
    const float* fb = feat + (size_t)b * FEAT * NPTS;
    for (int c0 = 0; c0 < FEAT; c0 += 64) {
        for (int e = t; e < 4096; e += 256) {
            const int c = e >> 6, nl = e & 63;
            As[c][nl] = f2bf(fb[(size_t)(c0 + c) * NPTS + n0 + nl]);
        }
        for (int e = t; e < 4096; e += 256) {
            const int fl = e >> 6, c = e & 63;
            Bs[c][fl] = f2bf(W[(size_t)(f0 + fl) * FEAT + c0 + c]);
        }
        __syncthreads();
        for (int c = 0; c < 64; ++c) {
            const ushort4 av = *(const ushort4*)&As[c][tn * 4];
            const ushort4 bv = *(const ushort4*)&Bs[c][tf * 4];
            float a[4], bb[4];
            a[0] = bf2f(av.x); a[1] = bf2f(av.y); a[2] = bf2f(av.z); a[3] = bf2f(av.w);
            bb[0] = bf2f(bv.x); bb[1] = bf2f(bv.y); bb[2] = bf2f(bv.z); bb[3] = bf2f(bv.w);
            for (int j = 0; j < 4; ++j)
                for (int i = 0; i < 4; ++i)
                    acc[j][i] = __builtin_fmaf(a[j], bb[i], acc[j][i]);
        }
        __syncthreads();
    }
    for (int j = 0; j < 4; ++j) {
        const int n = n0 + tn * 4 + j;
        ushort4 h;
        h.x = f2bf(acc[j][0] + bias[f0 + tf * 4 + 0]);
        h.y = f2bf(acc[j][1] + bias[f0 + tf * 4 + 1]);
        h.z = f2bf(acc[j][2] + bias[f0 + tf * 4 + 2]);
        h.w = f2bf(acc[j][3] + bias[f0 + tf * 4 + 3]);
        *(ushort4*)(Ht2 + ((size_t)b * NPTS + n) * FEAT + f0 + tf * 4) = h;
    }
}

// ---------------- count-weighted per-channel partial sums (bf16 in, f32 accum) ----
__global__ __launch_bounds__(256) void stats_partial(const unsigned short* __restrict__ Ht2,
                                                     const int* __restrict__ cnt,
                                                     float* __restrict__ part) {
    const int b = blockIdx.y;
    const int n0 = blockIdx.x * 64;
    const int f = threadIdx.x;
    float s = 0.f, s2 = 0.f;
    for (int nl = 0; nl < 64; ++nl) {
        const int n = n0 + nl;
        const float c = (float)cnt[b * NPTS + n];
        const float v = bf2f(Ht2[((size_t)b * NPTS + n) * FEAT + f]);
        s += c * v;
        s2 += c * v * v;
    }
    const int blk = b * 64 + blockIdx.x;  // [0, 256)
    part[blk * 512 + f] = s;
    part[blk * 512 + 256 + f] = s2;
}

// ---------------- BN finalize: 8 blocks x 32 channels, 8-way sub-reduction --------
__global__ __launch_bounds__(256) void stats_final(const float* __restrict__ part,
                                                   const float* __restrict__ gamma,
                                                   const float* __restrict__ beta,
                                                   float* __restrict__ sc,
                                                   float* __restrict__ sh) {
    __shared__ float ls[8][32], ls2[8][32];
    const int fl = (threadIdx.x & 31);
    const int f = blockIdx.x * 32 + fl;
    const int sub = threadIdx.x >> 5;  // 0..7
    float s = 0.f, s2 = 0.f;
    for (int blk = sub; blk < 256; blk += 8) {
        s += part[blk * 512 + f];
        s2 += part[blk * 512 + 256 + f];
    }
    ls[sub][fl] = s;
    ls2[sub][fl] = s2;
    __syncthreads();
    if (sub == 0) {
        for (int r = 1; r < 8; ++r) { s += ls[r][fl]; s2 += ls2[r][fl]; }
        const float inv = 1.0f / (float)(BATCH * NPTS * KNN);
        const float mean = s * inv;
        const float var = s2 * inv - mean * mean;
        const float scale = gamma[f] * rsqrtf(var + 1e-5f);
        sc[f] = scale;
        sh[f] = beta[f] - scale * mean;
    }
}

// ---------------- gather + affine + relu + max over K ----------------
// ushort4 gather: lane l owns f = 4l..4l+3; one wave = full 256-f row per (n,k).
// NOTE: the read MUST be ib[k*NPTS + n] — reference's raw (F,N*K)->(F,K,N) view.
#define NT 16
__global__ __launch_bounds__(256) void out_kernel(const unsigned short* __restrict__ Ht2,
                                                  const int* __restrict__ idx,
                                                  const float* __restrict__ sc,
                                                  const float* __restrict__ sh,
                                                  float* __restrict__ out) {
    __shared__ float tile[NT][FEAT + 1];
    const int b = blockIdx.y;
    const int n0 = blockIdx.x * NT;
    const int tid = threadIdx.x;
    const int w = tid >> 6, l = tid & 63;
    const float4 scl = *(const float4*)&sc[l * 4];
    const float4 shf = *(const float4*)&sh[l * 4];
    const unsigned short* Hb = Ht2 + (size_t)b * NPTS * FEAT;
    const int* ib = idx + (size_t)b * NPTS * KNN;
#pragma unroll
    for (int g = 0; g < 4; ++g) {
        const int nl = w * 4 + g;
        const int n = n0 + nl;
        float a0 = -1e30f, a1 = -1e30f, a2 = -1e30f, a3 = -1e30f;
        for (int k = 0; k < KNN; ++k) {
            const int u = ib[k * NPTS + n];  // wave-uniform -> scalar load
            const ushort4 h = *(const ushort4*)(Hb + (size_t)u * FEAT + l * 4);
            a0 = fmaxf(a0, __builtin_fmaf(bf2f(h.x), scl.x, shf.x));
            a1 = fmaxf(a1, __builtin_fmaf(bf2f(h.y), scl.y, shf.y));
            a2 = fmaxf(a2, __builtin_fmaf(bf2f(h.z), scl.z, shf.z));
            a3 = fmaxf(a3, __builtin_fmaf(bf2f(h.w), scl.w, shf.w));
        }
        tile[nl][l * 4 + 0] = fmaxf(a0, 0.0f);
        tile[nl][l * 4 + 1] = fmaxf(a1, 0.0f);
        tile[nl][l * 4 + 2] = fmaxf(a2, 0.0f);
        tile[nl][l * 4 + 3] = fmaxf(a3, 0.0f);
    }
    __syncthreads();
    const int nl2 = tid & (NT - 1);
    const int fbase = tid >> 4;  // 0..15
    for (int ff = 0; ff < FEAT; ff += 16) {
        const int f2 = fbase + ff;
        out[((size_t)b * FEAT + f2) * NPTS + n0 + nl2] = tile[nl2][f2];
    }
}

extern "C" void kernel_launch(void* const* d_in, const int* in_sizes, int n_in,
                              void* d_out, int out_size, void* d_ws, size_t ws_size,
                              hipStream_t stream) {
    (void)in_sizes; (void)n_in; (void)out_size; (void)ws_size;
    const float* xyz   = (const float*)d_in[0];
    const float* feat  = (const float*)d_in[1];
    const float* W     = (const float*)d_in[2];
    const float* bias  = (const float*)d_in[3];
    const float* gamma = (const float*)d_in[4];
    const float* beta  = (const float*)d_in[5];
    float* out = (float*)d_out;
    char* ws = (char*)d_ws;
    int*            idx  = (int*)(ws + OFF_IDX);
    int*            cnt  = (int*)(ws + OFF_CNT);
    float*          part = (float*)(ws + OFF_PART);
    float*          sc   = (float*)(ws + OFF_SC);
    float*          sh   = (float*)(ws + OFF_SH);
    unsigned short* Ht2  = (unsigned short*)(ws + OFF_HT2);

    (void)hipMemsetAsync(cnt, 0, BATCH * NPTS * sizeof(int), stream);
    fused_knn_gemm<<<dim3(3072), 256, 0, stream>>>(xyz, idx, cnt, feat, W, bias, Ht2);
    stats_partial<<<dim3(NPTS / 64, BATCH), 256, 0, stream>>>(Ht2, cnt, part);
    stats_final<<<8, 256, 0, stream>>>(part, gamma, beta, sc, sh);
    out_kernel<<<dim3(NPTS / NT, BATCH), 256, 0, stream>>>(Ht2, idx, sc, sh, out);
}

// Round 24
// 172.812 us; speedup vs baseline: 1.0614x; 1.0614x over previous
//
#include <hip/hip_runtime.h>
#include <cstdint>
#include <cstddef>

#define NPTS 4096
#define BATCH 4
#define FEAT 256
#define KNN 32

// ---------------- workspace layout (bytes) ----------------
static constexpr size_t OFF_IDX  = 0;                            // int32 [B*N*K]   = 2 MB
static constexpr size_t OFF_CNT  = 2u * 1024 * 1024;             // int32 [B*N]     = 64 KB
static constexpr size_t OFF_PART = OFF_CNT + 64u * 1024;         // f32 [256*512]   = 512 KB
static constexpr size_t OFF_SC   = OFF_PART + 512u * 1024;       // f32 [256]
static constexpr size_t OFF_SH   = OFF_SC + 4096;                // f32 [256]
static constexpr size_t OFF_HT2  = OFF_SH + 4096;                // bf16 [B*N*F]    = 8 MB

template<int CTRL>
static __device__ __forceinline__ uint32_t dpp32(uint32_t x) {
    return (uint32_t)__builtin_amdgcn_update_dpp(-1, (int)x, CTRL, 0xF, 0xF, false);
}

// full-wave u32 min; result returned uniform (via lane 63)
static __device__ __forceinline__ uint32_t wave_min_u32(uint32_t v) {
    v = min(v, dpp32<0x111>(v));  // row_shr:1
    v = min(v, dpp32<0x112>(v));  // row_shr:2
    v = min(v, dpp32<0x114>(v));  // row_shr:4
    v = min(v, dpp32<0x118>(v));  // row_shr:8
    v = min(v, dpp32<0x142>(v));  // row_bcast:15
    v = min(v, dpp32<0x143>(v));  // row_bcast:31
    return (uint32_t)__builtin_amdgcn_readlane((int)v, 63);
}

// fp32 -> bf16 round-to-nearest-even (finite values)
static __device__ __forceinline__ unsigned short f2bf(float x) {
    uint32_t u = __float_as_uint(x);
    u += 0x7FFFu + ((u >> 16) & 1u);
    return (unsigned short)(u >> 16);
}
static __device__ __forceinline__ float bf2f(unsigned short h) {
    return __uint_as_float(((uint32_t)h) << 16);
}

// ---------------- KNN body: TWO rows per wave (r14/r16 proven) --------------------
static __device__ __forceinline__ void knn_body2(int gid, const float* __restrict__ xyz,
                                                 int* __restrict__ out_idx,
                                                 int* __restrict__ cnt) {
#pragma clang fp contract(off)
    const int lane = threadIdx.x & 63;
    const int wv = threadIdx.x >> 6;       // 0..3
    const int b = gid >> 9;                // 512 knn-blocks per batch
    const int nA = (gid & 511) * 8 + wv * 2;
    const int nB = nA + 1;
    const float* xb = xyz + (size_t)b * 3 * NPTS;
    const float x0nA = xb[nA], x1nA = xb[NPTS + nA];
    const float sqnA = x0nA * x0nA + x1nA * x1nA;
    const float x0nB = xb[nB], x1nB = xb[NPTS + nB];
    const float sqnB = x0nB * x0nB + x1nB * x1nB;

    const float* xr0 = xb + lane * 64;
    const float* xr1 = xb + NPTS + lane * 64;
    const uint32_t mbase = (uint32_t)(lane * 64);

    uint32_t Ad0 = ~0u, Ad1 = ~0u, Ad2 = ~0u, Ad3 = ~0u;
    uint32_t Ai0 = 0, Ai1 = 0, Ai2 = 0, Ai3 = 0;
    uint32_t Bd0 = ~0u, Bd1 = ~0u, Bd2 = ~0u, Bd3 = ~0u;
    uint32_t Bi0 = 0, Bi1 = 0, Bi2 = 0, Bi3 = 0;

#define QINS(U, MI, D0, D1, D2, D3, I0, I1, I2, I3)                              \
    {                                                                            \
        const bool c0 = (U) < D0, c1 = (U) < D1, c2 = (U) < D2, c3 = (U) < D3;   \
        D3 = c3 ? (c2 ? D2 : (U)) : D3;   I3 = c3 ? (c2 ? I2 : (MI)) : I3;       \
        D2 = c2 ? (c1 ? D1 : (U)) : D2;   I2 = c2 ? (c1 ? I1 : (MI)) : I2;       \
        D1 = c1 ? (c0 ? D0 : (U)) : D1;   I1 = c1 ? (c0 ? I0 : (MI)) : I1;       \
        D0 = c0 ? (U) : D0;               I0 = c0 ? (MI) : I0;                   \
    }
#define UMAP(X0N, X1N, SQN, U)                                                   \
    uint32_t U; {                                                                \
        const float p = __builtin_fmaf((X1N), x1m, (X0N) * x0m);                 \
        const float d = __builtin_fmaf(p, -2.0f, sqm) + (SQN);                   \
        U = __float_as_uint(d);                                                  \
        U ^= (uint32_t)((int32_t)U >> 31) | 0x80000000u;                         \
    }

#pragma unroll 4
    for (int i0 = 0; i0 < 64; i0 += 4) {
        const float4 a0 = *(const float4*)(xr0 + i0);
        const float4 a1 = *(const float4*)(xr1 + i0);
#define CAND2(X0, X1, J)                                                         \
    {                                                                            \
        const float x0m = (X0), x1m = (X1);                                      \
        const float sqm = x0m * x0m + x1m * x1m;   /* shared, ref-identical */   \
        const uint32_t mi = mbase + (uint32_t)(i0 + (J));                        \
        UMAP(x0nA, x1nA, sqnA, uA)                                               \
        QINS(uA, mi, Ad0, Ad1, Ad2, Ad3, Ai0, Ai1, Ai2, Ai3)                     \
        UMAP(x0nB, x1nB, sqnB, uB)                                               \
        QINS(uB, mi, Bd0, Bd1, Bd2, Bd3, Bi0, Bi1, Bi2, Bi3)                     \
    }
        CAND2(a0.x, a1.x, 0)
        CAND2(a0.y, a1.y, 1)
        CAND2(a0.z, a1.z, 2)
        CAND2(a0.w, a1.w, 3)
#undef CAND2
    }

    int navA = 4, navB = 4;
    uint32_t widx = 0;  // lane k: A-winner k; lane 32+k: B-winner k
#pragma unroll 1
    for (int k = 0; k < KNN; ++k) {
        const uint32_t wdA = wave_min_u32(Ad0);
        const uint32_t wdB = wave_min_u32(Bd0);
        const unsigned long long balA = __ballot(Ad0 == wdA);
        const unsigned long long balB = __ballot(Bd0 == wdB);
        const int ownerA = __ffsll((long long)balA) - 1;
        const int ownerB = __ffsll((long long)balB) - 1;
        const uint32_t wmA = (uint32_t)__builtin_amdgcn_readlane((int)Ai0, ownerA);
        const uint32_t wmB = (uint32_t)__builtin_amdgcn_readlane((int)Bi0, ownerB);
        widx = (lane == k) ? wmA : widx;
        widx = (lane == k + 32) ? wmB : widx;
        const bool popA = (lane == ownerA);
        Ad0 = popA ? Ad1 : Ad0;  Ai0 = popA ? Ai1 : Ai0;
        Ad1 = popA ? Ad2 : Ad1;  Ai1 = popA ? Ai2 : Ai1;
        Ad2 = popA ? Ad3 : Ad2;  Ai2 = popA ? Ai3 : Ai2;
        Ad3 = popA ? 0xFFFFFFFFu : Ad3;
        navA -= popA ? 1 : 0;
        const bool popB = (lane == ownerB);
        Bd0 = popB ? Bd1 : Bd0;  Bi0 = popB ? Bi1 : Bi0;
        Bd1 = popB ? Bd2 : Bd1;  Bi1 = popB ? Bi2 : Bi1;
        Bd2 = popB ? Bd3 : Bd2;  Bi2 = popB ? Bi3 : Bi2;
        Bd3 = popB ? 0xFFFFFFFFu : Bd3;
        navB -= popB ? 1 : 0;
        if (navA == 0) {
            Ad0 = Ad1 = Ad2 = Ad3 = ~0u;
            Ai0 = Ai1 = Ai2 = Ai3 = 0;
#pragma unroll 4
            for (int i = 0; i < 64; ++i) {
                const float x0m = xr0[i], x1m = xr1[i];
                const float sqm = x0m * x0m + x1m * x1m;
                UMAP(x0nA, x1nA, sqnA, u)
                const uint32_t mi = mbase + (uint32_t)i;
                const bool keep = (u > wdA) || (u == wdA && mi > wmA);
                u = keep ? u : 0xFFFFFFFFu;
                QINS(u, mi, Ad0, Ad1, Ad2, Ad3, Ai0, Ai1, Ai2, Ai3)
            }
            navA = 4;
        }
        if (navB == 0) {
            Bd0 = Bd1 = Bd2 = Bd3 = ~0u;
            Bi0 = Bi1 = Bi2 = Bi3 = 0;
#pragma unroll 4
            for (int i = 0; i < 64; ++i) {
                const float x0m = xr0[i], x1m = xr1[i];
                const float sqm = x0m * x0m + x1m * x1m;
                UMAP(x0nB, x1nB, sqnB, u)
                const uint32_t mi = mbase + (uint32_t)i;
                const bool keep = (u > wdB) || (u == wdB && mi > wmB);
                u = keep ? u : 0xFFFFFFFFu;
                QINS(u, mi, Bd0, Bd1, Bd2, Bd3, Bi0, Bi1, Bi2, Bi3)
            }
            navB = 4;
        }
    }
    const int nw = (lane < 32) ? nA : nB;
    out_idx[((size_t)b * NPTS + nw) * KNN + (lane & 31)] = (int)widx;
    atomicAdd(&cnt[b * NPTS + (int)widx], 1);
#undef QINS
#undef UMAP
}

// ---------------- fused: knn blocks (2/3) + gemm blocks (1/3), r8 gemm ------------
__global__ __launch_bounds__(256, 4) void fused_knn_gemm(const float* __restrict__ xyz,
                                                         int* __restrict__ out_idx,
                                                         int* __restrict__ cnt,
                                                         const float* __restrict__ feat,
                                                         const float* __restrict__ W,
                                                         const float* __restrict__ bias,
                                                         unsigned short* __restrict__ Ht2) {
    const int bid = blockIdx.x;
    const int g3 = bid / 3, r3 = bid % 3;
    if (r3 < 2) {
        knn_body2(g3 * 2 + r3, xyz, out_idx, cnt);
        return;
    }
    // ---- gemm body (round-8 proven: c-tile 64, 33KB LDS) ----
    __shared__ float As[64][64];  // [c][n_local]
    __shared__ float Bs[64][65];  // [c][f_local], padded
    const int q = g3;             // [0, 1024)
    const int b = q >> 8;
    const int rr = q & 255;
    const int n0 = (rr >> 2) * 64;
    const int f0 = (rr & 3) * 64;
    const int t = threadIdx.x;
    const int tn = t % 16, tf = t / 16;
    float acc[4][4] = {};
    const float* fb = feat + (size_t)b * FEAT * NPTS;
    for (int c0 = 0; c0 < FEAT; c0 += 64) {
        for (int e = t; e < 4096; e += 256) {
            const int c = e >> 6, nl = e & 63;
            As[c][nl] = fb[(size_t)(c0 + c) * NPTS + n0 + nl];
        }
        for (int e = t; e < 4096; e += 256) {
            const int fl = e >> 6, c = e & 63;
            Bs[c][fl] = W[(size_t)(f0 + fl) * FEAT + c0 + c];
        }
        __syncthreads();
        for (int c = 0; c < 64; ++c) {
            float a[4], bb[4];
            for (int j = 0; j < 4; ++j) a[j] = As[c][tn * 4 + j];
            for (int i = 0; i < 4; ++i) bb[i] = Bs[c][tf * 4 + i];
            for (int j = 0; j < 4; ++j)
                for (int i = 0; i < 4; ++i)
                    acc[j][i] = __builtin_fmaf(a[j], bb[i], acc[j][i]);
        }
        __syncthreads();
    }
    for (int j = 0; j < 4; ++j) {
        const int n = n0 + tn * 4 + j;
        ushort4 h;
        h.x = f2bf(acc[j][0] + bias[f0 + tf * 4 + 0]);
        h.y = f2bf(acc[j][1] + bias[f0 + tf * 4 + 1]);
        h.z = f2bf(acc[j][2] + bias[f0 + tf * 4 + 2]);
        h.w = f2bf(acc[j][3] + bias[f0 + tf * 4 + 3]);
        *(ushort4*)(Ht2 + ((size_t)b * NPTS + n) * FEAT + f0 + tf * 4) = h;
    }
}

// ---------------- count-weighted per-channel partial sums (bf16 in, f32 accum) ----
__global__ __launch_bounds__(256) void stats_partial(const unsigned short* __restrict__ Ht2,
                                                     const int* __restrict__ cnt,
                                                     float* __restrict__ part) {
    const int b = blockIdx.y;
    const int n0 = blockIdx.x * 64;
    const int f = threadIdx.x;
    float s = 0.f, s2 = 0.f;
    for (int nl = 0; nl < 64; ++nl) {
        const int n = n0 + nl;
        const float c = (float)cnt[b * NPTS + n];
        const float v = bf2f(Ht2[((size_t)b * NPTS + n) * FEAT + f]);
        s += c * v;
        s2 += c * v * v;
    }
    const int blk = b * 64 + blockIdx.x;  // [0, 256)
    part[blk * 512 + f] = s;
    part[blk * 512 + 256 + f] = s2;
}

// ---------------- BN finalize: 8 blocks x 32 channels, 8-way sub-reduction --------
__global__ __launch_bounds__(256) void stats_final(const float* __restrict__ part,
                                                   const float* __restrict__ gamma,
                                                   const float* __restrict__ beta,
                                                   float* __restrict__ sc,
                                                   float* __restrict__ sh) {
    __shared__ float ls[8][32], ls2[8][32];
    const int fl = (threadIdx.x & 31);
    const int f = blockIdx.x * 32 + fl;
    const int sub = threadIdx.x >> 5;  // 0..7
    float s = 0.f, s2 = 0.f;
    for (int blk = sub; blk < 256; blk += 8) {
        s += part[blk * 512 + f];
        s2 += part[blk * 512 + 256 + f];
    }
    ls[sub][fl] = s;
    ls2[sub][fl] = s2;
    __syncthreads();
    if (sub == 0) {
        for (int r = 1; r < 8; ++r) { s += ls[r][fl]; s2 += ls2[r][fl]; }
        const float inv = 1.0f / (float)(BATCH * NPTS * KNN);
        const float mean = s * inv;
        const float var = s2 * inv - mean * mean;
        const float scale = gamma[f] * rsqrtf(var + 1e-5f);
        sc[f] = scale;
        sh[f] = beta[f] - scale * mean;
    }
}

// ---------------- gather + affine + relu + max over K ----------------
// ushort4 gather: lane l owns f = 4l..4l+3; one wave = full 256-f row per (n,k).
// NOTE: the read MUST be ib[k*NPTS + n] — reference's raw (F,N*K)->(F,K,N) view.
#define NT 16
__global__ __launch_bounds__(256) void out_kernel(const unsigned short* __restrict__ Ht2,
                                                  const int* __restrict__ idx,
                                                  const float* __restrict__ sc,
                                                  const float* __restrict__ sh,
                                                  float* __restrict__ out) {
    __shared__ float tile[NT][FEAT + 1];
    const int b = blockIdx.y;
    const int n0 = blockIdx.x * NT;
    const int tid = threadIdx.x;
    const int w = tid >> 6, l = tid & 63;
    const float4 scl = *(const float4*)&sc[l * 4];
    const float4 shf = *(const float4*)&sh[l * 4];
    const unsigned short* Hb = Ht2 + (size_t)b * NPTS * FEAT;
    const int* ib = idx + (size_t)b * NPTS * KNN;
#pragma unroll
    for (int g = 0; g < 4; ++g) {
        const int nl = w * 4 + g;
        const int n = n0 + nl;
        float a0 = -1e30f, a1 = -1e30f, a2 = -1e30f, a3 = -1e30f;
        for (int k = 0; k < KNN; ++k) {
            const int u = ib[k * NPTS + n];  // wave-uniform -> scalar load
            const ushort4 h = *(const ushort4*)(Hb + (size_t)u * FEAT + l * 4);
            a0 = fmaxf(a0, __builtin_fmaf(bf2f(h.x), scl.x, shf.x));
            a1 = fmaxf(a1, __builtin_fmaf(bf2f(h.y), scl.y, shf.y));
            a2 = fmaxf(a2, __builtin_fmaf(bf2f(h.z), scl.z, shf.z));
            a3 = fmaxf(a3, __builtin_fmaf(bf2f(h.w), scl.w, shf.w));
        }
        tile[nl][l * 4 + 0] = fmaxf(a0, 0.0f);
        tile[nl][l * 4 + 1] = fmaxf(a1, 0.0f);
        tile[nl][l * 4 + 2] = fmaxf(a2, 0.0f);
        tile[nl][l * 4 + 3] = fmaxf(a3, 0.0f);
    }
    __syncthreads();
    const int nl2 = tid & (NT - 1);
    const int fbase = tid >> 4;  // 0..15
    for (int ff = 0; ff < FEAT; ff += 16) {
        const int f2 = fbase + ff;
        out[((size_t)b * FEAT + f2) * NPTS + n0 + nl2] = tile[nl2][f2];
    }
}

extern "C" void kernel_launch(void* const* d_in, const int* in_sizes, int n_in,
                              void* d_out, int out_size, void* d_ws, size_t ws_size,
                              hipStream_t stream) {
    (void)in_sizes; (void)n_in; (void)out_size; (void)ws_size;
    const float* xyz   = (const float*)d_in[0];
    const float* feat  = (const float*)d_in[1];
    const float* W     = (const float*)d_in[2];
    const float* bias  = (const float*)d_in[3];
    const float* gamma = (const float*)d_in[4];
    const float* beta  = (const float*)d_in[5];
    float* out = (float*)d_out;
    char* ws = (char*)d_ws;
    int*            idx  = (int*)(ws + OFF_IDX);
    int*            cnt  = (int*)(ws + OFF_CNT);
    float*          part = (float*)(ws + OFF_PART);
    float*          sc   = (float*)(ws + OFF_SC);
    float*          sh   = (float*)(ws + OFF_SH);
    unsigned short* Ht2  = (unsigned short*)(ws + OFF_HT2);

    (void)hipMemsetAsync(cnt, 0, BATCH * NPTS * sizeof(int), stream);
    fused_knn_gemm<<<dim3(3072), 256, 0, stream>>>(xyz, idx, cnt, feat, W, bias, Ht2);
    stats_partial<<<dim3(NPTS / 64, BATCH), 256, 0, stream>>>(Ht2, cnt, part);
    stats_final<<<8, 256, 0, stream>>>(part, gamma, beta, sc, sh);
    out_kernel<<<dim3(NPTS / NT, BATCH), 256, 0, stream>>>(Ht2, idx, sc, sh, out);
}